// Round 3
// baseline (727.600 us; speedup 1.0000x reference)
//
#include <hip/hip_runtime.h>
#include <math.h>

// Problem constants
#define B_ 4
#define L_ 8192
#define D_ 1024
#define M_ (B_ * L_)   // 32768 rows
#define K_ D_          // 1024 reduction dim

// GEMM tiling: 128x128 out tile, BOTH gate+cand per block, BK=32, 4 waves
#define BM 128
#define BN 128
#define BK 32

// Scan chunking: one GEMM block row-tile == one chunk
#define NCH 64          // chunks per batch (L_/CHL)
#define CHL 128         // chunk length == BM

typedef short bf16x8 __attribute__((ext_vector_type(8)));
typedef float f32x4 __attribute__((ext_vector_type(4)));

__device__ __forceinline__ unsigned short f2bf(float f) {
    unsigned u = __float_as_uint(f);
    u += 0x7fff + ((u >> 16) & 1);   // RNE
    return (unsigned short)(u >> 16);
}
__device__ __forceinline__ float bf2f(unsigned short h) {
    return __uint_as_float(((unsigned)h) << 16);
}

__device__ __forceinline__ void async16(const void* g, void* l) {
    __builtin_amdgcn_global_load_lds(
        (const __attribute__((address_space(1))) unsigned int*)g,
        (__attribute__((address_space(3))) unsigned int*)l, 16, 0, 0);
}

// ---------------------------------------------------------------------------
// Weight prep: split Wg, Wc (fp32 [D,D]) into bf16 hi/lo planes.
// ---------------------------------------------------------------------------
__global__ __launch_bounds__(256) void wprep_kernel(
    const float* __restrict__ Wg, const float* __restrict__ Wc,
    unsigned short* __restrict__ Wghi, unsigned short* __restrict__ Wglo,
    unsigned short* __restrict__ Wchi, unsigned short* __restrict__ Wclo)
{
    int idx = (blockIdx.x * 256 + threadIdx.x) * 4;  // over 2*D*D elements
    const int n = D_ * D_;
    const float* src; unsigned short *dh, *dl; int o;
    if (idx < n) { src = Wg; dh = Wghi; dl = Wglo; o = idx; }
    else         { src = Wc; dh = Wchi; dl = Wclo; o = idx - n; }
    float4 v = *(const float4*)(src + o);
    ushort4 hi, lo;
    hi.x = f2bf(v.x); lo.x = f2bf(v.x - bf2f(hi.x));
    hi.y = f2bf(v.y); lo.y = f2bf(v.y - bf2f(hi.y));
    hi.z = f2bf(v.z); lo.z = f2bf(v.z - bf2f(hi.z));
    hi.w = f2bf(v.w); lo.w = f2bf(v.w - bf2f(hi.w));
    *(ushort4*)(dh + o) = hi;
    *(ushort4*)(dl + o) = lo;
}

// ---------------------------------------------------------------------------
// X prep: split X (fp32 [M,K]) into bf16 hi/lo planes (stored in d_out space,
// which scan_apply overwrites at the very end). Hoists the split VALU work
// out of the GEMM k-loop (was re-done 8x, once per n-block).
// ---------------------------------------------------------------------------
__global__ __launch_bounds__(256) void xprep_kernel(
    const float* __restrict__ X,
    unsigned short* __restrict__ Xhi, unsigned short* __restrict__ Xlo)
{
    size_t idx = ((size_t)blockIdx.x * 256 + threadIdx.x) * 4;
    float4 v = *(const float4*)(X + idx);
    ushort4 hi, lo;
    hi.x = f2bf(v.x); lo.x = f2bf(v.x - bf2f(hi.x));
    hi.y = f2bf(v.y); lo.y = f2bf(v.y - bf2f(hi.y));
    hi.z = f2bf(v.z); lo.z = f2bf(v.z - bf2f(hi.z));
    hi.w = f2bf(v.w); lo.w = f2bf(v.w - bf2f(hi.w));
    *(ushort4*)(Xhi + idx) = hi;
    *(ushort4*)(Xlo + idx) = lo;
}

// ---------------------------------------------------------------------------
// Fused dual GEMM (gate + cand in ONE block) + activation + in-register local
// scan over the 128-timestep chunk.
//
// This revision: ALL staging (A and B) via global_load_lds from pre-split
// bf16 planes -> near-zero VALU in the k-loop. A single-buffered, B
// double-buffered; per step issue 4 A-DMAs then 8 next-B-DMAs; counted
// s_waitcnt vmcnt(8) retires the 12 oldest (= B[s]+A[s]) while B[s+1]'s 8
// stay in flight across both barriers (never drain to 0 mid-loop).
// LDS = 16 KB (A) + 64 KB (B dbuf) = 80 KB -> 2 blocks/CU.
// ---------------------------------------------------------------------------
__global__ __launch_bounds__(256, 2) void gemm_scan_kernel(
    const unsigned short* __restrict__ Xhi, const unsigned short* __restrict__ Xlo,
    const unsigned short* __restrict__ Wghi, const unsigned short* __restrict__ Wglo,
    const unsigned short* __restrict__ Wchi, const unsigned short* __restrict__ Wclo,
    const float* __restrict__ bg, const float* __restrict__ bc,
    float* __restrict__ P_ws, float* __restrict__ h_ws,
    float* __restrict__ carryA, float* __restrict__ carryB)
{
    __shared__ __align__(16) unsigned short sAhi[BM * BK];      // 8 KB
    __shared__ __align__(16) unsigned short sAlo[BM * BK];      // 8 KB
    __shared__ __align__(16) unsigned short sB[2][4][BN * BK];  // 64 KB dbuf x {ghi,glo,chi,clo}

    const int t = threadIdx.x;
    const int lane = t & 63;
    const int w = t >> 6;          // wave 0..3
    const int wrow = w >> 1;       // 0..1  (m half)
    const int wcol = w & 1;        // 0..1  (n half)
    const int quad = lane >> 4;    // 0..3
    const int l16  = lane & 15;

    const int m0 = blockIdx.x * BM;
    const int n0 = blockIdx.y * BN;

    // staging geometry: thread t covers 16 B; 4 threads per 64 B row;
    // pass p adds 64 rows. kc = (t&3)*8 elements within the row.
    const int stRow = t >> 2;
    const int stKc  = (t & 3) << 3;
    const int stO   = t * 16;              // LDS byte offset (pass 0)

    f32x4 accg[4][4] = {};
    f32x4 accc[4][4] = {};

    unsigned short* sBc = &sB[0][0][0];    // current B buffer (4 planes)
    unsigned short* sBn = &sB[1][0][0];    // next B buffer

    // ---- prologue: stage B tile 0 into buffer 0 ----
#pragma unroll
    for (int p = 0; p < 2; ++p) {
        const int o = stO + p * 4096;
        const size_t gb = (size_t)(n0 + stRow + p * 64) * K_ + stKc;
        async16(Wghi + gb, (char*)sBc + o);
        async16(Wglo + gb, (char*)sBc + 8192 + o);
        async16(Wchi + gb, (char*)sBc + 16384 + o);
        async16(Wclo + gb, (char*)sBc + 24576 + o);
    }

#pragma unroll 1
    for (int s = 0; s < 32; ++s) {
        const int k0 = s * BK;

        // barrier #1: all waves done reading sA[s-1] and sBc[s-1]
        __builtin_amdgcn_s_barrier();

        // ---- A[s] staging into single buffer (4 DMAs, oldest this step) ----
#pragma unroll
        for (int p = 0; p < 2; ++p) {
            const int o = stO + p * 4096;
            const size_t ga = (size_t)(m0 + stRow + p * 64) * K_ + k0 + stKc;
            async16(Xhi + ga, (char*)sAhi + o);
            async16(Xlo + ga, (char*)sAlo + o);
        }

        // ---- B[s+1] staging into alt buffer (8 DMAs, stay in flight) ----
        if (s < 31) {
#pragma unroll
            for (int p = 0; p < 2; ++p) {
                const int o = stO + p * 4096;
                const size_t gb = (size_t)(n0 + stRow + p * 64) * K_ + (k0 + BK) + stKc;
                async16(Wghi + gb, (char*)sBn + o);
                async16(Wglo + gb, (char*)sBn + 8192 + o);
                async16(Wchi + gb, (char*)sBn + 16384 + o);
                async16(Wclo + gb, (char*)sBn + 24576 + o);
            }
            // retire the 12 oldest = B[s](8) + A[s](4); B[s+1](8) in flight
            asm volatile("s_waitcnt vmcnt(8)" ::: "memory");
        } else {
            asm volatile("s_waitcnt vmcnt(0)" ::: "memory");
        }
        __builtin_amdgcn_sched_barrier(0);

        // barrier #2: every wave's A[s]+B[s] DMAs retired
        __builtin_amdgcn_s_barrier();

        // ---- fragment loads + MFMA ----
        bf16x8 ahi[4], alo[4];
#pragma unroll
        for (int i = 0; i < 4; ++i) {
            const int off = (wrow * 64 + i * 16 + l16) * BK + quad * 8;
            ahi[i] = *(const bf16x8*)(sAhi + off);
            alo[i] = *(const bf16x8*)(sAlo + off);
        }
        __builtin_amdgcn_s_setprio(1);
#pragma unroll
        for (int j = 0; j < 4; ++j) {
            const int off = (wcol * 64 + j * 16 + l16) * BK + quad * 8;
            bf16x8 bgh = *(const bf16x8*)(sBc + off);
            bf16x8 bgl = *(const bf16x8*)(sBc + 4096 + off);
            bf16x8 bch = *(const bf16x8*)(sBc + 8192 + off);
            bf16x8 bcl = *(const bf16x8*)(sBc + 12288 + off);
#pragma unroll
            for (int i = 0; i < 4; ++i) {
                accg[i][j] = __builtin_amdgcn_mfma_f32_16x16x32_bf16(ahi[i], bgh, accg[i][j], 0, 0, 0);
                accg[i][j] = __builtin_amdgcn_mfma_f32_16x16x32_bf16(ahi[i], bgl, accg[i][j], 0, 0, 0);
                accg[i][j] = __builtin_amdgcn_mfma_f32_16x16x32_bf16(alo[i], bgh, accg[i][j], 0, 0, 0);
                accc[i][j] = __builtin_amdgcn_mfma_f32_16x16x32_bf16(ahi[i], bch, accc[i][j], 0, 0, 0);
                accc[i][j] = __builtin_amdgcn_mfma_f32_16x16x32_bf16(ahi[i], bcl, accc[i][j], 0, 0, 0);
                accc[i][j] = __builtin_amdgcn_mfma_f32_16x16x32_bf16(alo[i], bch, accc[i][j], 0, 0, 0);
            }
        }
        __builtin_amdgcn_s_setprio(0);

        // swap B buffers
        unsigned short* tmp = sBc; sBc = sBn; sBn = tmp;
        // no trailing barrier: next iteration's barrier #1 covers the hazard
    }

    // =======================================================================
    // Epilogue: bias + activation + in-register affine prefix scan over the
    // 128 timesteps of this chunk. Affine map per step: h -> g*h + c.
    // C/D layout [m89]: col(n) = l16, row(m within frag) = quad*4 + r.
    // =======================================================================
    const int b   = m0 >> 13;             // m0 / L_
    const int chk = (m0 & (L_ - 1)) >> 7; // chunk index within batch

    float RunA[4], RunB[4];               // per-j running carry (quad-replicated)
#pragma unroll
    for (int j = 0; j < 4; ++j) {
        const int n = n0 + wcol * 64 + j * 16 + l16;
        const float bgv = bg[n];
        const float bcv = bc[n];
        float Ar = 1.f, Br = 0.f;
#pragma unroll
        for (int i = 0; i < 4; ++i) {
            // local inclusive scan over this lane's 4 consecutive rows
            float P[4], H[4];
            float pp = 1.f, ph = 0.f;
#pragma unroll
            for (int r = 0; r < 4; ++r) {
                float zg = accg[i][j][r] + bgv;
                float zc = accc[i][j][r] + bcv;
                float g = 1.f / (1.f + __expf(-zg));
                float c = tanhf(zc);
                float Pv = (r == 0) ? g : g * pp;
                float Hv = (r == 0) ? c : fmaf(g, ph, c);
                P[r] = Pv; H[r] = Hv; pp = Pv; ph = Hv;
            }
            // cross-quad inclusive scan of lane totals (P[3],H[3])
            float Ai = P[3], Bi = H[3];
            float A1 = __shfl(Ai, (lane - 16) & 63);
            float B1 = __shfl(Bi, (lane - 16) & 63);
            if (quad >= 1) { Bi = fmaf(Ai, B1, Bi); Ai *= A1; }
            float A2 = __shfl(Ai, (lane - 32) & 63);
            float B2 = __shfl(Bi, (lane - 32) & 63);
            if (quad >= 2) { Bi = fmaf(Ai, B2, Bi); Ai *= A2; }
            // exclusive prefix for this quad = inclusive of quad-1
            float Ae = __shfl(Ai, (lane - 16) & 63);
            float Be = __shfl(Bi, (lane - 16) & 63);
            if (quad == 0) { Ae = 1.f; Be = 0.f; }
            // pre-compose: C = E_quad ∘ Run
            float Ca = Ae * Ar;
            float Cb = fmaf(Ae, Br, Be);
            // element prefix = local ∘ C  -> write back (P, hloc) into acc
#pragma unroll
            for (int r = 0; r < 4; ++r) {
                float Pr = P[r];
                accg[i][j][r] = Pr * Ca;
                accc[i][j][r] = fmaf(Pr, Cb, H[r]);
            }
            // advance Run by the full 16-row group (quad 3 inclusive total)
            float Ag  = __shfl(Ai, l16 + 48);
            float Bg2 = __shfl(Bi, l16 + 48);
            Br = fmaf(Ag, Br, Bg2);
            Ar *= Ag;
        }
        RunA[j] = Ar; RunB[j] = Br;
    }

    // ---- cross-wave carry exchange: cw overlays sAhi (16 KB >> 1 KB) ----
    __syncthreads();   // all waves done with sAhi frag reads before reuse
    float* cwf = (float*)sAhi;   // layout [2][4][16][2]

    if (wrow == 0 && quad == 0) {
#pragma unroll
        for (int j = 0; j < 4; ++j) {
            cwf[(((wcol * 4 + j) * 16 + l16) << 1) + 0] = RunA[j];
            cwf[(((wcol * 4 + j) * 16 + l16) << 1) + 1] = RunB[j];
        }
    }
    __syncthreads();
    if (wrow == 1) {
#pragma unroll
        for (int j = 0; j < 4; ++j) {
            float Aw = cwf[(((wcol * 4 + j) * 16 + l16) << 1) + 0];
            float Bw = cwf[(((wcol * 4 + j) * 16 + l16) << 1) + 1];
#pragma unroll
            for (int i = 0; i < 4; ++i) {
#pragma unroll
                for (int r = 0; r < 4; ++r) {
                    float Pe = accg[i][j][r];
                    accc[i][j][r] = fmaf(Pe, Bw, accc[i][j][r]);
                    accg[i][j][r] = Pe * Aw;
                }
            }
            if (quad == 0) {   // one lane set per channel writes chunk carry
                const int n = n0 + wcol * 64 + j * 16 + l16;
                size_t co = (((size_t)b * NCH + chk) << 10) + n;
                carryA[co] = RunA[j] * Aw;
                carryB[co] = fmaf(RunA[j], Bw, RunB[j]);
            }
        }
    }

    // ---- stores: P and hloc in [m][n] layout ----
#pragma unroll
    for (int j = 0; j < 4; ++j) {
        const int n = n0 + wcol * 64 + j * 16 + l16;
#pragma unroll
        for (int i = 0; i < 4; ++i) {
#pragma unroll
            for (int r = 0; r < 4; ++r) {
                int m = m0 + wrow * 64 + i * 16 + quad * 4 + r;
                size_t o = ((size_t)m << 10) + n;
                P_ws[o] = accg[i][j][r];
                h_ws[o] = accc[i][j][r];
            }
        }
    }
}

// ---------------------------------------------------------------------------
// Kernel: exclusive scan of chunk carries; carryB[k] <- h entering chunk k.
// ---------------------------------------------------------------------------
__global__ __launch_bounds__(256) void scan_carry_kernel(
    const float* __restrict__ carryA, float* __restrict__ carryB)
{
    const int idx = blockIdx.x * 256 + threadIdx.x;  // B_*D_ threads
    const int b = idx >> 10;
    const int d = idx & (D_ - 1);
    float acc = 0.f;
    for (int k = 0; k < NCH; ++k) {
        const size_t o = (((size_t)b * NCH + k) << 10) + d;
        const float a  = carryA[o];
        const float bb = carryB[o];
        carryB[o] = acc;
        acc = fmaf(a, acc, bb);
    }
}

// ---------------------------------------------------------------------------
// Kernel: elementwise apply: out = hloc + P * h_in  (pure streaming)
// ---------------------------------------------------------------------------
__global__ __launch_bounds__(256) void scan_apply_kernel(
    const float* __restrict__ P_ws, const float* __restrict__ h_ws,
    const float* __restrict__ carryB, float* __restrict__ out)
{
    const size_t o = ((size_t)blockIdx.x * 256 + threadIdx.x) * 4;
    const int m  = (int)(o >> 10);
    const int d  = (int)(o & (D_ - 1));
    const int b  = m >> 13;
    const int ch = (m & (L_ - 1)) >> 7;
    const float4 hin = *(const float4*)(carryB + ((((size_t)b * NCH + ch) << 10) + d));
    const float4 P = *(const float4*)(P_ws + o);
    const float4 H = *(const float4*)(h_ws + o);
    float4 r;
    r.x = fmaf(P.x, hin.x, H.x);
    r.y = fmaf(P.y, hin.y, H.y);
    r.z = fmaf(P.z, hin.z, H.z);
    r.w = fmaf(P.w, hin.w, H.w);
    *(float4*)(out + o) = r;
}

// ---------------------------------------------------------------------------
extern "C" void kernel_launch(void* const* d_in, const int* in_sizes, int n_in,
                              void* d_out, int out_size, void* d_ws, size_t ws_size,
                              hipStream_t stream)
{
    const float* x  = (const float*)d_in[0];
    const float* Wg = (const float*)d_in[1];
    const float* bg = (const float*)d_in[2];
    const float* Wc = (const float*)d_in[3];
    const float* bc = (const float*)d_in[4];
    float* out = (float*)d_out;

    // Workspace layout (unchanged, ~278 MB):
    //   P_ws   fp32 M*D      134.2 MB
    //   h_ws   fp32 M*D      134.2 MB
    //   carryA fp32 B*NCH*D    1 MB
    //   carryB fp32 B*NCH*D    1 MB
    //   Wghi/Wglo/Wchi/Wclo  bf16 D*D  2 MB each
    // Xhi/Xlo bf16 planes (134.2 MB total) live in d_out, which is only
    // overwritten by scan_apply at the very end (stream-ordered).
    float* ws = (float*)d_ws;
    float* P_ws   = ws;
    float* h_ws   = P_ws + (size_t)M_ * D_;
    float* carryA = h_ws + (size_t)M_ * D_;
    float* carryB = carryA + (size_t)B_ * NCH * D_;
    unsigned short* Wghi = (unsigned short*)(carryB + (size_t)B_ * NCH * D_);
    unsigned short* Wglo = Wghi + (size_t)D_ * D_;
    unsigned short* Wchi = Wglo + (size_t)D_ * D_;
    unsigned short* Wclo = Wchi + (size_t)D_ * D_;

    unsigned short* Xhi = (unsigned short*)out;        // 67.1 MB
    unsigned short* Xlo = Xhi + (size_t)M_ * D_;       // 67.1 MB (exactly fills d_out)

    wprep_kernel<<<(2 * D_ * D_ / 4) / 256, 256, 0, stream>>>(
        Wg, Wc, Wghi, Wglo, Wchi, Wclo);

    xprep_kernel<<<((size_t)M_ * D_ / 4) / 256, 256, 0, stream>>>(x, Xhi, Xlo);

    gemm_scan_kernel<<<dim3(M_ / BM, D_ / BN), 256, 0, stream>>>(
        Xhi, Xlo, Wghi, Wglo, Wchi, Wclo, bg, bc, P_ws, h_ws, carryA, carryB);

    scan_carry_kernel<<<(B_ * D_) / 256, 256, 0, stream>>>(carryA, carryB);

    scan_apply_kernel<<<(M_ * (D_ / 4)) / 256, 256, 0, stream>>>(
        P_ws, h_ws, carryB, out);
}